// Round 1
// baseline (52.047 us; speedup 1.0000x reference)
//
#include <hip/hip_runtime.h>
#include <hip/hip_bf16.h>

// Problem constants (from reference): B=8192, MN=64*64=4096, D=128
#define NB   8192
#define NMN  4096
#define ND   128

typedef __attribute__((ext_vector_type(8))) short bf16x8;  // 8 bf16 = 4 VGPRs
typedef __attribute__((ext_vector_type(4))) float f32x4;

// ---------------------------------------------------------------------------
// Prepass: fp32 -> bf16 conversion + exact fp32 row-norms.
// One block of 128 threads per row (batch rows first, then weight rows).
// ---------------------------------------------------------------------------
__global__ __launch_bounds__(128) void som_prep(const float* __restrict__ batch,
                                                const float* __restrict__ weights,
                                                __hip_bfloat16* __restrict__ abf,
                                                __hip_bfloat16* __restrict__ bbf,
                                                float* __restrict__ a2,
                                                float* __restrict__ b2) {
    const int row = blockIdx.x;
    const float* src;
    __hip_bfloat16* dst;
    float* norm;
    if (row < NB) {
        src = batch + (size_t)row * ND;
        dst = abf + (size_t)row * ND;
        norm = a2 + row;
    } else {
        const int r = row - NB;
        src = weights + (size_t)r * ND;
        dst = bbf + (size_t)r * ND;
        norm = b2 + r;
    }
    const int t = threadIdx.x;
    const float v = src[t];
    dst[t] = __float2bfloat16(v);

    float p = v * v;
    // wave-64 butterfly reduce
    #pragma unroll
    for (int off = 32; off > 0; off >>= 1) p += __shfl_down(p, off, 64);

    __shared__ float s[2];
    if ((t & 63) == 0) s[t >> 6] = p;
    __syncthreads();
    if (t == 0) norm[0] = s[0] + s[1];
}

// ---------------------------------------------------------------------------
// Main GEMM: out[b][m] = a2[b] + b2[m] - 2 * dot(A[b], W[m])
// 128x128 block tile, 256 threads = 4 waves in 2x2, each wave owns 64x64.
// K = 128 -> 4 k-steps of mfma_f32_16x16x32_bf16; acc[4][4] f32x4 per lane.
// No LDS: fragments are 16B contiguous K-slices, loaded direct from
// L2-resident bf16 copies (A row-major, B^T row-major both give contiguous
// per-lane fragments for the gfx950 16x16x32 layout).
// ---------------------------------------------------------------------------
__global__ __launch_bounds__(256) void som_gemm(const __hip_bfloat16* __restrict__ abf,
                                                const __hip_bfloat16* __restrict__ bbf,
                                                const float* __restrict__ a2,
                                                const float* __restrict__ b2,
                                                float* __restrict__ out) {
    const int bx   = blockIdx.x;
    const int brow = (bx >> 5) << 7;   // (bx / 32) * 128 ; 8192/128 = 64 row-blocks
    const int bcol = (bx & 31) << 7;   // (bx % 32) * 128 ; 4096/128 = 32 col-blocks

    const int tid  = threadIdx.x;
    const int lane = tid & 63;
    const int wid  = tid >> 6;
    const int wr   = wid >> 1;         // wave row 0..1
    const int wc   = wid & 1;          // wave col 0..1
    const int l15  = lane & 15;
    const int l4   = lane >> 4;

    const bf16x8* A8 = reinterpret_cast<const bf16x8*>(abf);
    const bf16x8* B8 = reinterpret_cast<const bf16x8*>(bbf);

    // element-of-8 indices; row stride = ND/8 = 16
    // A fragment: row = (brow + wr*64 + m*16 + l15), k8 = kk*4 + l4
    const int abase = (brow + wr * 64 + l15) * (ND / 8) + l4;
    const int bbase = (bcol + wc * 64 + l15) * (ND / 8) + l4;

    f32x4 acc[4][4];
    #pragma unroll
    for (int m = 0; m < 4; ++m)
        #pragma unroll
        for (int n = 0; n < 4; ++n)
            acc[m][n] = (f32x4){0.f, 0.f, 0.f, 0.f};

    #pragma unroll
    for (int kk = 0; kk < 4; ++kk) {
        bf16x8 af[4], bfr[4];
        #pragma unroll
        for (int m = 0; m < 4; ++m) af[m] = A8[abase + m * 256 + kk * 4];
        #pragma unroll
        for (int n = 0; n < 4; ++n) bfr[n] = B8[bbase + n * 256 + kk * 4];
        #pragma unroll
        for (int m = 0; m < 4; ++m)
            #pragma unroll
            for (int n = 0; n < 4; ++n)
                acc[m][n] = __builtin_amdgcn_mfma_f32_16x16x32_bf16(af[m], bfr[n], acc[m][n], 0, 0, 0);
    }

    // Epilogue: C/D mapping col = lane&15, row = (lane>>4)*4 + reg
    const int orow0 = brow + wr * 64 + l4 * 4;
    const int ocol0 = bcol + wc * 64 + l15;

    float b2v[4];
    #pragma unroll
    for (int n = 0; n < 4; ++n) b2v[n] = b2[ocol0 + n * 16];

    #pragma unroll
    for (int m = 0; m < 4; ++m) {
        #pragma unroll
        for (int r = 0; r < 4; ++r) {
            const int row = orow0 + m * 16 + r;
            const float av = a2[row];
            float* __restrict__ orow = out + (size_t)row * NMN;
            #pragma unroll
            for (int n = 0; n < 4; ++n) {
                orow[ocol0 + n * 16] = av + b2v[n] - 2.0f * acc[m][n][r];
            }
        }
    }
}

// ---------------------------------------------------------------------------
extern "C" void kernel_launch(void* const* d_in, const int* in_sizes, int n_in,
                              void* d_out, int out_size, void* d_ws, size_t ws_size,
                              hipStream_t stream) {
    const float* batch   = (const float*)d_in[0];   // (8192, 128) fp32
    const float* weights = (const float*)d_in[1];   // (4096, 128) fp32
    float* out = (float*)d_out;                     // (8192, 4096) fp32

    // workspace layout (16B-aligned regions):
    //   a2  : 8192 * 4          =   32768 B @ 0
    //   b2  : 4096 * 4          =   16384 B @ 32768
    //   abf : 8192 * 128 * 2    = 2097152 B @ 49152
    //   bbf : 4096 * 128 * 2    = 1048576 B @ 2146304
    // total ~3.05 MB
    char* ws = (char*)d_ws;
    float* a2 = (float*)(ws);
    float* b2 = (float*)(ws + 32768);
    __hip_bfloat16* abf = (__hip_bfloat16*)(ws + 49152);
    __hip_bfloat16* bbf = (__hip_bfloat16*)(ws + 49152 + 2097152);

    som_prep<<<dim3(NB + NMN), dim3(128), 0, stream>>>(batch, weights, abf, bbf, a2, b2);

    // grid: 64 row-blocks * 32 col-blocks = 2048 blocks
    som_gemm<<<dim3(2048), dim3(256), 0, stream>>>(abf, bbf, a2, b2, out);
}